// Round 11
// baseline (191.068 us; speedup 1.0000x reference)
//
#include <hip/hip_runtime.h>
#include <hip/hip_bf16.h>
#include <math.h>

#define B_TOT 16384
#define NPART 16
#define NPAIR 120     // 16*15/2
#define HID   64
#define DL    5
#define GB    2       // batch elements per block (serialized through s_h)
#define PSI_ROWS 120  // psi h1 rows resident per iteration
#define PHI_HROW 120  // phi h1 rows live at s_h rows [120,136)
#define NROW_IT  136
#define SF_PHI   240  // phi feature rows in s_f at [240,272)

typedef __attribute__((ext_vector_type(8))) short short8;
typedef __attribute__((ext_vector_type(4))) float floatx4;

// FMA-only GELU (0 transcendentals): tanh-GELU with degree-7 odd minimax
// tanh poly on [-3,3], input clamp +-3, output clamp +-1 (v_med3_f32).
// Max dev from exact GELU ~0.02 — same class as the sigmoid-GELU used in
// R5-R10 (also ~0.02), which has held absmax at the 0.25 bf16 quantum.
// 11 full-rate VALU, no v_exp/v_rcp: discriminating probe on trans-op rate.
__device__ __forceinline__ float gelu_poly(float v) {
    float v2 = v * v;
    float u  = v * __builtin_fmaf(v2, 0.03567741f, 0.79788456f);
    u = __builtin_amdgcn_fmed3f(u, -3.0f, 3.0f);
    float u2 = u * u;
    float p  = __builtin_fmaf(u2, -0.00162457f, 0.0315144f);
    p = __builtin_fmaf(u2, p, -0.222068f);
    p = __builtin_fmaf(u2, p, 0.96203f);
    float t  = u * p;
    t = __builtin_amdgcn_fmed3f(t, -1.0f, 1.0f);
    float hv = 0.5f * v;
    return __builtin_fmaf(hv, t, hv);
}

__device__ __forceinline__ unsigned pk2(float a, float b) {
    __hip_bfloat162 h = __float22bfloat162_rn(make_float2(a, b));
    union { __hip_bfloat162 h; unsigned u; } cv; cv.h = h;
    return cv.u;
}

__device__ __forceinline__ unsigned short f2bfbits(float f) {
    __hip_bfloat16 h = __float2bfloat16(f);
    union { __hip_bfloat16 h; unsigned short u; } cv; cv.h = h;
    return cv.u;
}

__device__ __forceinline__ float wred(float v) {
    v += __shfl_down(v, 32);
    v += __shfl_down(v, 16);
    v += __shfl_down(v, 8);
    v += __shfl_down(v, 4);
    v += __shfl_down(v, 2);
    v += __shfl_down(v, 1);
    return v;
}

// Block = 2 batch elements, 256 threads (4 waves). LDS ~21.8 KB.
// h1 layout: stride 64, XOR swizzle (row,col) -> s_h[row*64 + (col ^ ((row&7)<<3))].
// Layer-1 and layer-2 via MFMA 16x16x32 bf16; layer-3 folded into column sums
// (row-mean commutes with matmul). Cusp exact fp32.
__global__ __launch_bounds__(256) void jastrow_mfma8(
    const float* __restrict__ x,
    const float* __restrict__ phi_w0, const float* __restrict__ phi_b0,
    const float* __restrict__ phi_w1, const float* __restrict__ phi_b1,
    const float* __restrict__ phi_w2, const float* __restrict__ phi_b2,
    const float* __restrict__ psi_w0, const float* __restrict__ psi_b0,
    const float* __restrict__ psi_w1, const float* __restrict__ psi_b1,
    const float* __restrict__ psi_w2, const float* __restrict__ psi_b2,
    const float* __restrict__ rho_w0, const float* __restrict__ rho_b0,
    const float* __restrict__ rho_w1, const float* __restrict__ rho_b1,
    float* __restrict__ out)
{
    const int t    = threadIdx.x;
    const int lane = t & 63;
    const int wv   = t >> 6;
    const int q    = lane >> 4;
    const int m15  = lane & 15;
    const int bg   = blockIdx.x * GB;

    __shared__ __align__(16) unsigned short s_h[NROW_IT * 64];   // 17408 B
    __shared__ __align__(16) unsigned char  s_mem[4352];         // s_f | s_cs
    __shared__ float s_cusp[4];

    unsigned short* s_f  = (unsigned short*)s_mem;  // [272][8] bf16 features
    float*          s_cs = (float*)s_mem;           // [2][GB][4][4][16] colsum partials

    const float2* x2 = (const float2*)x;
    float cusp = 0.f;

    // ================= Phase 0: features (both batches) -> s_f =================
    {
        const int bl = t >> 7;
        const int p  = t & 127;
        if (p < NPAIR) {
            int u = 119 - p;
            float sq = sqrtf((float)(8 * u + 1));
            int k = (int)((sq - 1.0f) * 0.5f);
            int i = 14 - k;
            int j = p - (i * (31 - i)) / 2 + i + 1;

            float2 xi = x2[(bg + bl) * NPART + i];
            float2 xj = x2[(bg + bl) * NPART + j];
            float dx = xi.x - xj.x, dy = xi.y - xj.y;
            float r = sqrtf(dx * dx + dy * dy + 1e-12f);

            // f0=log1p(r), f1=r/(1+r), f2=exp(-r^2), f3=exp(-r/2), f4=exp(-r), f5=exp(-2r)
            float f0 = 0.69314718056f * __builtin_amdgcn_logf(1.f + r);
            float f1 = r * __builtin_amdgcn_rcpf(1.f + r);
            float f3 = __builtin_amdgcn_exp2f(-0.72134752044f * r);
            float f4 = f3 * f3;
            float f5 = f4 * f4;
            float f2 = __builtin_amdgcn_exp2f(-1.44269504089f * r * r);
            cusp = r * f4;                    // exact fp32

            union { short8 s; unsigned u4[4]; } v;
            v.u4[0] = pk2(f0, f1);
            v.u4[1] = pk2(f2, f3);
            v.u4[2] = pk2(f4, f5);
            v.u4[3] = 0u;
            *(short8*)&s_f[(bl * PSI_ROWS + p) * 8] = v.s;
        }
        if (t < GB * NPART) {                 // 32 phi feature rows
            int bl2 = t >> 4, n = t & 15;
            float2 xv = x2[(bg + bl2) * NPART + n];
            float r2 = xv.x * xv.x + xv.y * xv.y;
            union { short8 s; unsigned u4[4]; } w;
            w.u4[0] = pk2(xv.x, xv.y);
            w.u4[1] = pk2(r2, 0.f);
            w.u4[2] = 0u; w.u4[3] = 0u;
            *(short8*)&s_f[(SF_PHI + t) * 8] = w.s;
        }
    }

    const int colb = wv * 16 + m15;           // this lane's output column
    int swz[4];
#pragma unroll
    for (int rg = 0; rg < 4; ++rg) swz[rg] = colb ^ (((q * 4 + rg) & 7) << 3);

    // --------- hoisted B-fragments + biases (live across both iterations) ------
    short8 Bp1 = (short8)0, Bf1 = (short8)0;
    if (q == 0) {
        union { short8 s; unsigned u4[4]; } bb;
        const float* w = psi_w0 + colb * 6;
        bb.u4[0] = pk2(w[0], w[1]); bb.u4[1] = pk2(w[2], w[3]);
        bb.u4[2] = pk2(w[4], w[5]); bb.u4[3] = 0u;
        Bp1 = bb.s;
        const float* wf = phi_w0 + colb * 3;
        bb.u4[0] = pk2(wf[0], wf[1]); bb.u4[1] = pk2(wf[2], 0.f);
        bb.u4[2] = 0u; bb.u4[3] = 0u;
        Bf1 = bb.s;
    }
    float b0p = psi_b0[colb], b0f = phi_b0[colb];
    floatx4 C0p = {b0p, b0p, b0p, b0p};
    floatx4 C0f = {b0f, b0f, b0f, b0f};

    short8 Bp2[2], Bf2[2];
#pragma unroll
    for (int Kc = 0; Kc < 2; ++Kc) {
        int k0 = Kc * 32 + q * 8;
        const float* wp = psi_w1 + colb * HID + k0;
        const float* wf = phi_w1 + colb * HID + k0;
        union { short8 s; unsigned u4[4]; } bp, bf;
#pragma unroll
        for (int e2 = 0; e2 < 4; ++e2) {
            bp.u4[e2] = pk2(wp[e2 * 2], wp[e2 * 2 + 1]);
            bf.u4[e2] = pk2(wf[e2 * 2], wf[e2 * 2 + 1]);
        }
        Bp2[Kc] = bp.s; Bf2[Kc] = bf.s;
    }
    float b1p = psi_b1[colb], b1f = phi_b1[colb];
    floatx4 C1p = {b1p, b1p, b1p, b1p};
    floatx4 C1f = {b1f, b1f, b1f, b1f};

    // swizzled A-read offsets for layer-2 (row&7 = m15&7; all row bases %8==0)
    const int g0 = ((q ^ (m15 & 7)) << 3);
    const int g1 = g0 ^ 32;

    float csP[GB] = {0.f, 0.f};
    float csF[GB] = {0.f, 0.f};

    __syncthreads();   // s_f ready

    // ================= serialized per-batch iterations =========================
#pragma unroll
    for (int bl = 0; bl < GB; ++bl) {
        // ---- Phase 1: layer-1 MFMA + gelu + swizzled scatter into s_h --------
#pragma unroll
        for (int Mt = 0; Mt < 8; ++Mt) {
            short8 a = (short8)0;
            if (q == 0) a = *(const short8*)&s_f[(bl * PSI_ROWS + Mt * 16 + m15) * 8];
            floatx4 d = __builtin_amdgcn_mfma_f32_16x16x32_bf16(a, Bp1, C0p, 0, 0, 0);
            if (Mt < 7 || q < 2) {   // D-rows 120..127 don't exist -> skip
#pragma unroll
                for (int rg = 0; rg < 4; ++rg)
                    s_h[(Mt * 16 + q * 4 + rg) * 64 + swz[rg]] =
                        f2bfbits(gelu_poly(d[rg]));
            }
        }
        {
            short8 a = (short8)0;
            if (q == 0) a = *(const short8*)&s_f[(SF_PHI + bl * 16 + m15) * 8];
            floatx4 d = __builtin_amdgcn_mfma_f32_16x16x32_bf16(a, Bf1, C0f, 0, 0, 0);
#pragma unroll
            for (int rg = 0; rg < 4; ++rg)
                s_h[(PHI_HROW + q * 4 + rg) * 64 + swz[rg]] =
                    f2bfbits(gelu_poly(d[rg]));
        }
        __syncthreads();   // h1 ready

        // ---- Phase 2+3: layer-2 MFMA + gelu + colsum accumulate ---------------
#pragma unroll
        for (int Mt = 0; Mt < 8; ++Mt) {
            int rb = (Mt * 16 + m15) * 64;
            short8 a0 = *(const short8*)&s_h[rb + g0];
            short8 a1 = *(const short8*)&s_h[rb + g1];
            floatx4 acc = __builtin_amdgcn_mfma_f32_16x16x32_bf16(a0, Bp2[0], C1p, 0, 0, 0);
            acc = __builtin_amdgcn_mfma_f32_16x16x32_bf16(a1, Bp2[1], acc, 0, 0, 0);
            if (Mt == 7) {
                if (q < 2) {       // D-rows 120..127 are garbage (phi region) -> exclude
#pragma unroll
                    for (int rg = 0; rg < 4; ++rg)
                        csP[bl] += gelu_poly(acc[rg]);
                }
            } else {
#pragma unroll
                for (int rg = 0; rg < 4; ++rg)
                    csP[bl] += gelu_poly(acc[rg]);
            }
        }
        {
            int rb = (PHI_HROW + m15) * 64;
            short8 a0 = *(const short8*)&s_h[rb + g0];
            short8 a1 = *(const short8*)&s_h[rb + g1];
            floatx4 acc = __builtin_amdgcn_mfma_f32_16x16x32_bf16(a0, Bf2[0], C1f, 0, 0, 0);
            acc = __builtin_amdgcn_mfma_f32_16x16x32_bf16(a1, Bf2[1], acc, 0, 0, 0);
#pragma unroll
            for (int rg = 0; rg < 4; ++rg)
                csF[bl] += gelu_poly(acc[rg]);
        }
        __syncthreads();   // s_h consumed; safe to overwrite next iteration
    }

    // ---- store colsum partials (s_f dead -> s_cs aliases it) ------------------
#pragma unroll
    for (int bl = 0; bl < GB; ++bl) {
        s_cs[(((0 * GB + bl) * 4 + wv) * 4 + q) * 16 + m15] = csP[bl];
        s_cs[(((1 * GB + bl) * 4 + wv) * 4 + q) * 16 + m15] = csF[bl];
    }
    {
        float cc = wred(cusp);
        if (lane == 0) s_cusp[wv] = cc;
    }
    __syncthreads();

    // ================= Phase 4: readout (wave 0 -> b0, wave 1 -> b1) ===========
    if (t < 128) {
        const int blr = wv;
        const int c   = lane;
        const int cw  = c >> 4, cm = c & 15;
        float colP = 0.f, colF = 0.f;
#pragma unroll
        for (int qq = 0; qq < 4; ++qq) {
            colP += s_cs[(((0 * GB + blr) * 4 + cw) * 4 + qq) * 16 + cm];
            colF += s_cs[(((1 * GB + blr) * 4 + cw) * 4 + qq) * 16 + cm];
        }

        float psiv[DL], phiv[DL];
#pragma unroll
        for (int d = 0; d < DL; ++d) {
            float sP = wred(colP * psi_w2[d * HID + c]);
            psiv[d] = __shfl(sP, 0) * (1.0f / NPAIR) + psi_b2[d];
            float sF = wred(colF * phi_w2[d * HID + c]);
            phiv[d] = __shfl(sF, 0) * (1.0f / NPART) + phi_b2[d];
        }

        int j = lane;
        float a = rho_b0[j];
        const float* wr = rho_w0 + j * (2 * DL);
#pragma unroll
        for (int d = 0; d < DL; ++d)
            a += phiv[d] * wr[d] + psiv[d] * wr[DL + d];
        float cuspb = s_cusp[2 * blr] + s_cusp[2 * blr + 1];
        float cv = gelu_poly(a) * rho_w1[j];
        cv = wred(cv);
        if (j == 0) out[bg + blr] = cv + rho_b1[0] + cuspb;
    }
}

extern "C" void kernel_launch(void* const* d_in, const int* in_sizes, int n_in,
                              void* d_out, int out_size, void* d_ws, size_t ws_size,
                              hipStream_t stream) {
    const float* x      = (const float*)d_in[0];
    const float* phi_w0 = (const float*)d_in[1];
    const float* phi_b0 = (const float*)d_in[2];
    const float* phi_w1 = (const float*)d_in[3];
    const float* phi_b1 = (const float*)d_in[4];
    const float* phi_w2 = (const float*)d_in[5];
    const float* phi_b2 = (const float*)d_in[6];
    const float* psi_w0 = (const float*)d_in[7];
    const float* psi_b0 = (const float*)d_in[8];
    const float* psi_w1 = (const float*)d_in[9];
    const float* psi_b1 = (const float*)d_in[10];
    const float* psi_w2 = (const float*)d_in[11];
    const float* psi_b2 = (const float*)d_in[12];
    const float* rho_w0 = (const float*)d_in[13];
    const float* rho_b0 = (const float*)d_in[14];
    const float* rho_w1 = (const float*)d_in[15];
    const float* rho_b1 = (const float*)d_in[16];

    jastrow_mfma8<<<B_TOT / GB, 256, 0, stream>>>(
        x,
        phi_w0, phi_b0, phi_w1, phi_b1, phi_w2, phi_b2,
        psi_w0, psi_b0, psi_w1, psi_b1, psi_w2, psi_b2,
        rho_w0, rho_b0, rho_w1, rho_b1,
        (float*)d_out);
}

// Round 12
// 179.211 us; speedup vs baseline: 1.0662x; 1.0662x over previous
//
#include <hip/hip_runtime.h>
#include <hip/hip_bf16.h>
#include <math.h>

#define B_TOT 16384
#define NPART 16
#define NPAIR 120     // 16*15/2
#define HID   64
#define DL    5
#define GB    2       // batch elements per block (serialized through s_h)
#define PSI_ROWS 120  // psi h1 rows resident per iteration
#define PHI_HROW 120  // phi h1 rows live at s_h rows [120,136)
#define NROW_IT  136
#define SF_PHI   240  // phi feature rows in s_f at [240,272)

typedef __attribute__((ext_vector_type(8))) short short8;
typedef __attribute__((ext_vector_type(4))) float floatx4;

// Sigmoid-GELU: v * sigmoid(1.702 v) = v * rcp(1 + 2^(-2.4556 v)).
// 3 full-rate VALU + 2 trans (v_exp_f32, v_rcp_f32). R11's FMA-only poly
// (11 full-rate, 0 trans) was 15% SLOWER: the trans pipe overlaps plain
// VALU issue on gfx950 (VALUBusy read 117%), so this is the minimal form.
__device__ __forceinline__ float gelu_sig(float v) {
    float e = __builtin_amdgcn_exp2f(-2.45556851f * v);
    return v * __builtin_amdgcn_rcpf(1.0f + e);
}

__device__ __forceinline__ unsigned pk2(float a, float b) {
    __hip_bfloat162 h = __float22bfloat162_rn(make_float2(a, b));
    union { __hip_bfloat162 h; unsigned u; } cv; cv.h = h;
    return cv.u;
}

__device__ __forceinline__ unsigned short f2bfbits(float f) {
    __hip_bfloat16 h = __float2bfloat16(f);
    union { __hip_bfloat16 h; unsigned short u; } cv; cv.h = h;
    return cv.u;
}

__device__ __forceinline__ float wred(float v) {
    v += __shfl_down(v, 32);
    v += __shfl_down(v, 16);
    v += __shfl_down(v, 8);
    v += __shfl_down(v, 4);
    v += __shfl_down(v, 2);
    v += __shfl_down(v, 1);
    return v;
}

// Block = 2 batch elements, 256 threads (4 waves). LDS ~21.8 KB -> 7 blocks/CU.
// h1 layout: stride 64, XOR swizzle (row,col) -> s_h[row*64 + (col ^ ((row&7)<<3))].
// Layer-1 and layer-2 via MFMA 16x16x32 bf16; layer-3 folded into column sums
// (row-mean commutes with matmul). Cusp exact fp32. Trans via raw v_exp/v_log.
// == R10 kernel (best measured: 110.6 us), restored after R11 regression. ==
__global__ __launch_bounds__(256) void jastrow_mfma9(
    const float* __restrict__ x,
    const float* __restrict__ phi_w0, const float* __restrict__ phi_b0,
    const float* __restrict__ phi_w1, const float* __restrict__ phi_b1,
    const float* __restrict__ phi_w2, const float* __restrict__ phi_b2,
    const float* __restrict__ psi_w0, const float* __restrict__ psi_b0,
    const float* __restrict__ psi_w1, const float* __restrict__ psi_b1,
    const float* __restrict__ psi_w2, const float* __restrict__ psi_b2,
    const float* __restrict__ rho_w0, const float* __restrict__ rho_b0,
    const float* __restrict__ rho_w1, const float* __restrict__ rho_b1,
    float* __restrict__ out)
{
    const int t    = threadIdx.x;
    const int lane = t & 63;
    const int wv   = t >> 6;
    const int q    = lane >> 4;
    const int m15  = lane & 15;
    const int bg   = blockIdx.x * GB;

    __shared__ __align__(16) unsigned short s_h[NROW_IT * 64];   // 17408 B
    __shared__ __align__(16) unsigned char  s_mem[4352];         // s_f | s_cs
    __shared__ float s_cusp[4];

    unsigned short* s_f  = (unsigned short*)s_mem;  // [272][8] bf16 features
    float*          s_cs = (float*)s_mem;           // [2][GB][4][4][16] colsum partials

    const float2* x2 = (const float2*)x;
    float cusp = 0.f;

    // ================= Phase 0: features (both batches) -> s_f =================
    {
        const int bl = t >> 7;
        const int p  = t & 127;
        if (p < NPAIR) {
            int u = 119 - p;
            float sq = sqrtf((float)(8 * u + 1));
            int k = (int)((sq - 1.0f) * 0.5f);
            int i = 14 - k;
            int j = p - (i * (31 - i)) / 2 + i + 1;

            float2 xi = x2[(bg + bl) * NPART + i];
            float2 xj = x2[(bg + bl) * NPART + j];
            float dx = xi.x - xj.x, dy = xi.y - xj.y;
            float r = sqrtf(dx * dx + dy * dy + 1e-12f);

            // f0=log1p(r), f1=r/(1+r), f2=exp(-r^2), f3=exp(-r/2), f4=exp(-r), f5=exp(-2r)
            float f0 = 0.69314718056f * __builtin_amdgcn_logf(1.f + r);
            float f1 = r * __builtin_amdgcn_rcpf(1.f + r);
            float f3 = __builtin_amdgcn_exp2f(-0.72134752044f * r);
            float f4 = f3 * f3;
            float f5 = f4 * f4;
            float f2 = __builtin_amdgcn_exp2f(-1.44269504089f * r * r);
            cusp = r * f4;                    // exact fp32

            union { short8 s; unsigned u4[4]; } v;
            v.u4[0] = pk2(f0, f1);
            v.u4[1] = pk2(f2, f3);
            v.u4[2] = pk2(f4, f5);
            v.u4[3] = 0u;
            *(short8*)&s_f[(bl * PSI_ROWS + p) * 8] = v.s;
        }
        if (t < GB * NPART) {                 // 32 phi feature rows
            int bl2 = t >> 4, n = t & 15;
            float2 xv = x2[(bg + bl2) * NPART + n];
            float r2 = xv.x * xv.x + xv.y * xv.y;
            union { short8 s; unsigned u4[4]; } w;
            w.u4[0] = pk2(xv.x, xv.y);
            w.u4[1] = pk2(r2, 0.f);
            w.u4[2] = 0u; w.u4[3] = 0u;
            *(short8*)&s_f[(SF_PHI + t) * 8] = w.s;
        }
    }

    const int colb = wv * 16 + m15;           // this lane's output column
    int swz[4];
#pragma unroll
    for (int rg = 0; rg < 4; ++rg) swz[rg] = colb ^ (((q * 4 + rg) & 7) << 3);

    // --------- hoisted B-fragments + biases (live across both iterations) ------
    short8 Bp1 = (short8)0, Bf1 = (short8)0;
    if (q == 0) {
        union { short8 s; unsigned u4[4]; } bb;
        const float* w = psi_w0 + colb * 6;
        bb.u4[0] = pk2(w[0], w[1]); bb.u4[1] = pk2(w[2], w[3]);
        bb.u4[2] = pk2(w[4], w[5]); bb.u4[3] = 0u;
        Bp1 = bb.s;
        const float* wf = phi_w0 + colb * 3;
        bb.u4[0] = pk2(wf[0], wf[1]); bb.u4[1] = pk2(wf[2], 0.f);
        bb.u4[2] = 0u; bb.u4[3] = 0u;
        Bf1 = bb.s;
    }
    float b0p = psi_b0[colb], b0f = phi_b0[colb];
    floatx4 C0p = {b0p, b0p, b0p, b0p};
    floatx4 C0f = {b0f, b0f, b0f, b0f};

    short8 Bp2[2], Bf2[2];
#pragma unroll
    for (int Kc = 0; Kc < 2; ++Kc) {
        int k0 = Kc * 32 + q * 8;
        const float* wp = psi_w1 + colb * HID + k0;
        const float* wf = phi_w1 + colb * HID + k0;
        union { short8 s; unsigned u4[4]; } bp, bf;
#pragma unroll
        for (int e2 = 0; e2 < 4; ++e2) {
            bp.u4[e2] = pk2(wp[e2 * 2], wp[e2 * 2 + 1]);
            bf.u4[e2] = pk2(wf[e2 * 2], wf[e2 * 2 + 1]);
        }
        Bp2[Kc] = bp.s; Bf2[Kc] = bf.s;
    }
    float b1p = psi_b1[colb], b1f = phi_b1[colb];
    floatx4 C1p = {b1p, b1p, b1p, b1p};
    floatx4 C1f = {b1f, b1f, b1f, b1f};

    // swizzled A-read offsets for layer-2 (row&7 = m15&7; all row bases %8==0)
    const int g0 = ((q ^ (m15 & 7)) << 3);
    const int g1 = g0 ^ 32;

    float csP[GB] = {0.f, 0.f};
    float csF[GB] = {0.f, 0.f};

    __syncthreads();   // s_f ready

    // ================= serialized per-batch iterations =========================
#pragma unroll
    for (int bl = 0; bl < GB; ++bl) {
        // ---- Phase 1: layer-1 MFMA + gelu + swizzled scatter into s_h --------
#pragma unroll
        for (int Mt = 0; Mt < 8; ++Mt) {
            short8 a = (short8)0;
            if (q == 0) a = *(const short8*)&s_f[(bl * PSI_ROWS + Mt * 16 + m15) * 8];
            floatx4 d = __builtin_amdgcn_mfma_f32_16x16x32_bf16(a, Bp1, C0p, 0, 0, 0);
            if (Mt < 7 || q < 2) {   // D-rows 120..127 don't exist -> skip
#pragma unroll
                for (int rg = 0; rg < 4; ++rg)
                    s_h[(Mt * 16 + q * 4 + rg) * 64 + swz[rg]] =
                        f2bfbits(gelu_sig(d[rg]));
            }
        }
        {
            short8 a = (short8)0;
            if (q == 0) a = *(const short8*)&s_f[(SF_PHI + bl * 16 + m15) * 8];
            floatx4 d = __builtin_amdgcn_mfma_f32_16x16x32_bf16(a, Bf1, C0f, 0, 0, 0);
#pragma unroll
            for (int rg = 0; rg < 4; ++rg)
                s_h[(PHI_HROW + q * 4 + rg) * 64 + swz[rg]] =
                    f2bfbits(gelu_sig(d[rg]));
        }
        __syncthreads();   // h1 ready

        // ---- Phase 2+3: layer-2 MFMA + gelu + colsum accumulate ---------------
#pragma unroll
        for (int Mt = 0; Mt < 8; ++Mt) {
            int rb = (Mt * 16 + m15) * 64;
            short8 a0 = *(const short8*)&s_h[rb + g0];
            short8 a1 = *(const short8*)&s_h[rb + g1];
            floatx4 acc = __builtin_amdgcn_mfma_f32_16x16x32_bf16(a0, Bp2[0], C1p, 0, 0, 0);
            acc = __builtin_amdgcn_mfma_f32_16x16x32_bf16(a1, Bp2[1], acc, 0, 0, 0);
            if (Mt == 7) {
                if (q < 2) {       // D-rows 120..127 are garbage (phi region) -> exclude
#pragma unroll
                    for (int rg = 0; rg < 4; ++rg)
                        csP[bl] += gelu_sig(acc[rg]);
                }
            } else {
#pragma unroll
                for (int rg = 0; rg < 4; ++rg)
                    csP[bl] += gelu_sig(acc[rg]);
            }
        }
        {
            int rb = (PHI_HROW + m15) * 64;
            short8 a0 = *(const short8*)&s_h[rb + g0];
            short8 a1 = *(const short8*)&s_h[rb + g1];
            floatx4 acc = __builtin_amdgcn_mfma_f32_16x16x32_bf16(a0, Bf2[0], C1f, 0, 0, 0);
            acc = __builtin_amdgcn_mfma_f32_16x16x32_bf16(a1, Bf2[1], acc, 0, 0, 0);
#pragma unroll
            for (int rg = 0; rg < 4; ++rg)
                csF[bl] += gelu_sig(acc[rg]);
        }
        __syncthreads();   // s_h consumed; safe to overwrite next iteration
    }

    // ---- store colsum partials (s_f dead -> s_cs aliases it) ------------------
#pragma unroll
    for (int bl = 0; bl < GB; ++bl) {
        s_cs[(((0 * GB + bl) * 4 + wv) * 4 + q) * 16 + m15] = csP[bl];
        s_cs[(((1 * GB + bl) * 4 + wv) * 4 + q) * 16 + m15] = csF[bl];
    }
    {
        float cc = wred(cusp);
        if (lane == 0) s_cusp[wv] = cc;
    }
    __syncthreads();

    // ================= Phase 4: readout (wave 0 -> b0, wave 1 -> b1) ===========
    if (t < 128) {
        const int blr = wv;
        const int c   = lane;
        const int cw  = c >> 4, cm = c & 15;
        float colP = 0.f, colF = 0.f;
#pragma unroll
        for (int qq = 0; qq < 4; ++qq) {
            colP += s_cs[(((0 * GB + blr) * 4 + cw) * 4 + qq) * 16 + cm];
            colF += s_cs[(((1 * GB + blr) * 4 + cw) * 4 + qq) * 16 + cm];
        }

        float psiv[DL], phiv[DL];
#pragma unroll
        for (int d = 0; d < DL; ++d) {
            float sP = wred(colP * psi_w2[d * HID + c]);
            psiv[d] = __shfl(sP, 0) * (1.0f / NPAIR) + psi_b2[d];
            float sF = wred(colF * phi_w2[d * HID + c]);
            phiv[d] = __shfl(sF, 0) * (1.0f / NPART) + phi_b2[d];
        }

        int j = lane;
        float a = rho_b0[j];
        const float* wr = rho_w0 + j * (2 * DL);
#pragma unroll
        for (int d = 0; d < DL; ++d)
            a += phiv[d] * wr[d] + psiv[d] * wr[DL + d];
        float cuspb = s_cusp[2 * blr] + s_cusp[2 * blr + 1];
        float cv = gelu_sig(a) * rho_w1[j];
        cv = wred(cv);
        if (j == 0) out[bg + blr] = cv + rho_b1[0] + cuspb;
    }
}

extern "C" void kernel_launch(void* const* d_in, const int* in_sizes, int n_in,
                              void* d_out, int out_size, void* d_ws, size_t ws_size,
                              hipStream_t stream) {
    const float* x      = (const float*)d_in[0];
    const float* phi_w0 = (const float*)d_in[1];
    const float* phi_b0 = (const float*)d_in[2];
    const float* phi_w1 = (const float*)d_in[3];
    const float* phi_b1 = (const float*)d_in[4];
    const float* phi_w2 = (const float*)d_in[5];
    const float* phi_b2 = (const float*)d_in[6];
    const float* psi_w0 = (const float*)d_in[7];
    const float* psi_b0 = (const float*)d_in[8];
    const float* psi_w1 = (const float*)d_in[9];
    const float* psi_b1 = (const float*)d_in[10];
    const float* psi_w2 = (const float*)d_in[11];
    const float* psi_b2 = (const float*)d_in[12];
    const float* rho_w0 = (const float*)d_in[13];
    const float* rho_b0 = (const float*)d_in[14];
    const float* rho_w1 = (const float*)d_in[15];
    const float* rho_b1 = (const float*)d_in[16];

    jastrow_mfma9<<<B_TOT / GB, 256, 0, stream>>>(
        x,
        phi_w0, phi_b0, phi_w1, phi_b1, phi_w2, phi_b2,
        psi_w0, psi_b0, psi_w1, psi_b1, psi_w2, psi_b2,
        rho_w0, rho_b0, rho_w1, rho_b1,
        (float*)d_out);
}